// Round 5
// baseline (244.341 us; speedup 1.0000x reference)
//
#include <hip/hip_runtime.h>

#define DIM 128
#define NUM_OUT 100000
#define OFFS_BYTES (((4 * (NUM_OUT + 1)) + 511) / 512 * 512)

typedef float v2f __attribute__((ext_vector_type(2)));
typedef float v4f __attribute__((ext_vector_type(4)));

__device__ __forceinline__ float fast_tanh(float x) {
  const float xc = fminf(fmaxf(x, -15.f), 15.f);
  const float t = __expf(2.f * xc);
  return __fdividef(t - 1.f, t + 1.f);
}

// Kernel 0: segment boundaries. offs[s] = first edge e with seg[e] >= s.
__global__ __launch_bounds__(256) void build_offs(
    const int* __restrict__ seg, int* __restrict__ offs, int n_edges, int n_out) {
  const int e = blockIdx.x * 256 + threadIdx.x;
  if (e >= n_edges) return;
  const int se = seg[e];
  const int sp = (e == 0) ? -1 : seg[e - 1];
  for (int s = sp + 1; s <= se; ++s) offs[s] = e;
  if (e == n_edges - 1) {
    for (int s = se + 1; s <= n_out; ++s) offs[s] = n_edges;
  }
}

// Kernel 1: per-segment gather+sum. 128 threads = 2 waves = 2 segments/block.
// Streaming traffic (gidx, g) is non-temporal so `values` stays L3-resident.
__global__ __launch_bounds__(128) void seg_gather_sum(
    const float* __restrict__ values,
    const int* __restrict__ gidx,
    const int* __restrict__ offs,
    float* __restrict__ g,
    int n_edges) {
  const int s = blockIdx.x * 2 + (threadIdx.x >> 6);
  const int t = threadIdx.x & 63;

  int e0 = __builtin_amdgcn_readfirstlane(offs[s]);
  int e1 = __builtin_amdgcn_readfirstlane(offs[s + 1]);
  const int len = e1 - e0;

  const v2f* __restrict__ v2 = (const v2f*)values;
  float accx = 0.f, accy = 0.f;

  for (int base = 0; base < len; base += 64) {
    // one coalesced nt load covers up to 64 edge indices for this window
    const int my = __builtin_nontemporal_load(&gidx[min(e0 + base + t, n_edges - 1)]);
    const int n = min(64, len - base);
    int k = 0;
    for (; k + 8 <= n; k += 8) {
      int r0 = __builtin_amdgcn_readlane(my, k + 0);
      int r1 = __builtin_amdgcn_readlane(my, k + 1);
      int r2 = __builtin_amdgcn_readlane(my, k + 2);
      int r3 = __builtin_amdgcn_readlane(my, k + 3);
      int r4 = __builtin_amdgcn_readlane(my, k + 4);
      int r5 = __builtin_amdgcn_readlane(my, k + 5);
      int r6 = __builtin_amdgcn_readlane(my, k + 6);
      int r7 = __builtin_amdgcn_readlane(my, k + 7);
      const v2f a0 = v2[(size_t)r0 * (DIM / 2) + t];
      const v2f a1 = v2[(size_t)r1 * (DIM / 2) + t];
      const v2f a2 = v2[(size_t)r2 * (DIM / 2) + t];
      const v2f a3 = v2[(size_t)r3 * (DIM / 2) + t];
      const v2f a4 = v2[(size_t)r4 * (DIM / 2) + t];
      const v2f a5 = v2[(size_t)r5 * (DIM / 2) + t];
      const v2f a6 = v2[(size_t)r6 * (DIM / 2) + t];
      const v2f a7 = v2[(size_t)r7 * (DIM / 2) + t];
      accx += a0.x + a1.x + a2.x + a3.x + a4.x + a5.x + a6.x + a7.x;
      accy += a0.y + a1.y + a2.y + a3.y + a4.y + a5.y + a6.y + a7.y;
    }
    if (k < n) {
      const int nm1 = n - 1;
#pragma unroll
      for (int j = 0; j < 7; j += 4) {
        if (k + j < n) {
          int q0 = __builtin_amdgcn_readlane(my, min(k + j + 0, nm1));
          int q1 = __builtin_amdgcn_readlane(my, min(k + j + 1, nm1));
          int q2 = __builtin_amdgcn_readlane(my, min(k + j + 2, nm1));
          int q3 = __builtin_amdgcn_readlane(my, min(k + j + 3, nm1));
          const float m1 = (k + j + 1 < n) ? 1.f : 0.f;
          const float m2 = (k + j + 2 < n) ? 1.f : 0.f;
          const float m3 = (k + j + 3 < n) ? 1.f : 0.f;
          const v2f b0 = v2[(size_t)q0 * (DIM / 2) + t];
          const v2f b1 = v2[(size_t)q1 * (DIM / 2) + t];
          const v2f b2 = v2[(size_t)q2 * (DIM / 2) + t];
          const v2f b3 = v2[(size_t)q3 * (DIM / 2) + t];
          accx += b0.x + m1 * b1.x + m2 * b2.x + m3 * b3.x;
          accy += b0.y + m1 * b1.y + m2 * b2.y + m3 * b3.y;
        }
      }
    }
  }

  v2f r;
  r.x = accx;
  r.y = accy;
  __builtin_nontemporal_store(r, &((v2f*)g)[(size_t)s * (DIM / 2) + t]);
}

// Kernel 2: out = tanh(g @ W). Register-tiled, no LDS. d-step 4, v4f g
// loads, nt on streamed g/out so W (and values) keep the caches.
__global__ __launch_bounds__(256) void gemm_tanh(
    const float* __restrict__ g,
    const float* __restrict__ W,
    float* __restrict__ out,
    int n_rows) {
  const int lane = threadIdx.x & 63;
  const int wv = threadIdx.x >> 6;   // 0..3
  const int h = lane >> 5;           // 0..1
  const int tx = lane & 31;          // 0..31
  const int f = tx * 4;              // output col base
  const int r0 = blockIdx.x * 64 + wv * 16 + h * 8;

  const float* gp[8];
#pragma unroll
  for (int r = 0; r < 8; ++r) {
    int rr = r0 + r;
    rr = rr < n_rows ? rr : n_rows - 1;
    gp[r] = g + (size_t)rr * DIM;
  }

  float acc[8][4] = {};
#pragma unroll 1
  for (int d = 0; d < DIM; d += 4) {
    const v4f w0 = *(const v4f*)(W + (d + 0) * DIM + f);
    const v4f w1 = *(const v4f*)(W + (d + 1) * DIM + f);
    const v4f w2 = *(const v4f*)(W + (d + 2) * DIM + f);
    const v4f w3 = *(const v4f*)(W + (d + 3) * DIM + f);
    v4f gv[8];
#pragma unroll
    for (int r = 0; r < 8; ++r)
      gv[r] = __builtin_nontemporal_load((const v4f*)(gp[r] + d));
#pragma unroll
    for (int r = 0; r < 8; ++r) {
      acc[r][0] = fmaf(gv[r].x, w0.x, acc[r][0]);
      acc[r][1] = fmaf(gv[r].x, w0.y, acc[r][1]);
      acc[r][2] = fmaf(gv[r].x, w0.z, acc[r][2]);
      acc[r][3] = fmaf(gv[r].x, w0.w, acc[r][3]);
      acc[r][0] = fmaf(gv[r].y, w1.x, acc[r][0]);
      acc[r][1] = fmaf(gv[r].y, w1.y, acc[r][1]);
      acc[r][2] = fmaf(gv[r].y, w1.z, acc[r][2]);
      acc[r][3] = fmaf(gv[r].y, w1.w, acc[r][3]);
      acc[r][0] = fmaf(gv[r].z, w2.x, acc[r][0]);
      acc[r][1] = fmaf(gv[r].z, w2.y, acc[r][1]);
      acc[r][2] = fmaf(gv[r].z, w2.z, acc[r][2]);
      acc[r][3] = fmaf(gv[r].z, w2.w, acc[r][3]);
      acc[r][0] = fmaf(gv[r].w, w3.x, acc[r][0]);
      acc[r][1] = fmaf(gv[r].w, w3.y, acc[r][1]);
      acc[r][2] = fmaf(gv[r].w, w3.z, acc[r][2]);
      acc[r][3] = fmaf(gv[r].w, w3.w, acc[r][3]);
    }
  }

#pragma unroll
  for (int r = 0; r < 8; ++r) {
    const int rr = r0 + r;
    if (rr < n_rows) {
      v4f o;
      o.x = fast_tanh(acc[r][0]);
      o.y = fast_tanh(acc[r][1]);
      o.z = fast_tanh(acc[r][2]);
      o.w = fast_tanh(acc[r][3]);
      __builtin_nontemporal_store(o, (v4f*)(out + (size_t)rr * DIM + f));
    }
  }
}

extern "C" void kernel_launch(void* const* d_in, const int* in_sizes, int n_in,
                              void* d_out, int out_size, void* d_ws, size_t ws_size,
                              hipStream_t stream) {
  const float* values = (const float*)d_in[0];   // [N_SRC, 128] f32
  const float* W      = (const float*)d_in[1];   // [128, 128] f32
  const int*   gidx   = (const int*)d_in[2];     // [E] int
  const int*   seg    = (const int*)d_in[3];     // [E] int, sorted
  float* out = (float*)d_out;                    // [N_OUT, 128] f32

  int*   offs = (int*)d_ws;                          // [N_OUT+1]
  float* g    = (float*)((char*)d_ws + OFFS_BYTES);  // [N_OUT, 128] f32

  const int n_edges = in_sizes[2];

  build_offs<<<(n_edges + 255) / 256, 256, 0, stream>>>(seg, offs, n_edges, NUM_OUT);
  seg_gather_sum<<<NUM_OUT / 2, 128, 0, stream>>>(values, gidx, offs, g, n_edges);
  gemm_tanh<<<(NUM_OUT + 63) / 64, 256, 0, stream>>>(g, W, out, NUM_OUT);
}